// Round 5
// baseline (396.764 us; speedup 1.0000x reference)
//
#include <hip/hip_runtime.h>
#include <hip/hip_bf16.h>

#define BB    4
#define NN    1024
#define DM    1024
#define HH    16
#define HID   512
#define TT    (BB * NN)

typedef __attribute__((ext_vector_type(8))) short bf16x8;
typedef __attribute__((ext_vector_type(4))) float f32x4;

__device__ __forceinline__ ushort f2bfu(float f) {
    __hip_bfloat16 h = __float2bfloat16(f);
    return __builtin_bit_cast(ushort, h);
}

__device__ __forceinline__ float bfu2f(ushort u) {
    __hip_bfloat16 h = __builtin_bit_cast(__hip_bfloat16, u);
    return __bfloat162float(h);
}

__device__ __forceinline__ f32x4 mfma16(bf16x8 a, bf16x8 b, f32x4 c) {
    return __builtin_amdgcn_mfma_f32_16x16x32_bf16(a, b, c, 0, 0, 0);
}

// async 16B/lane global->LDS; lds dest = wave-uniform base + lane*16
__device__ __forceinline__ void gll16(const void* g, void* l) {
    __builtin_amdgcn_global_load_lds(
        (const __attribute__((address_space(1))) unsigned int*)g,
        (__attribute__((address_space(3))) unsigned int*)l, 16, 0, 0);
}

// ---------------------------------------------------------------------------
// Mask dtype detector (vectorized): flags[0]=any nonzero byte at pos%4!=0,
// flags[1]=any nonzero byte at pos%4==0 over the first 4 MiB.
// ---------------------------------------------------------------------------
__global__ void detect_mask_kernel(const uint4* __restrict__ m,
                                   int n16, int* __restrict__ flags) {
    int stride = blockDim.x * gridDim.x;
    unsigned hi = 0, lo = 0;
    for (int i = blockIdx.x * blockDim.x + threadIdx.x; i < n16; i += stride) {
        uint4 v = m[i];
        unsigned o = v.x | v.y | v.z | v.w;
        lo |= o & 0xFFu;
        hi |= o & 0xFFFFFF00u;
    }
    if (hi) atomicOr(&flags[0], 1);
    if (lo) atomicOr(&flags[1], 1);
}

// ---------------------------------------------------------------------------
// Batched f32->bf16 convert: NS equal-size segments (n4 float4s each).
// ---------------------------------------------------------------------------
template <int NS>
struct CvtArgs { const float* s[NS]; ushort* d[NS]; };

template <int NS>
__global__ __launch_bounds__(256) void cvt_multi(CvtArgs<NS> a, int n4) {
    int total = n4 * NS;
    int stride = blockDim.x * gridDim.x;
    for (int i = blockIdx.x * blockDim.x + threadIdx.x; i < total; i += stride) {
        const float* sp = a.s[0];
        ushort* dp = a.d[0];
        #pragma unroll
        for (int k = 1; k < NS; ++k) {
            bool ge = i >= k * n4;
            sp = ge ? a.s[k] : sp;
            dp = ge ? a.d[k] : dp;
        }
        int j = i % n4;
        float4 v = ((const float4*)sp)[j];
        uint2 o;
        o.x = (unsigned)f2bfu(v.x) | ((unsigned)f2bfu(v.y) << 16);
        o.y = (unsigned)f2bfu(v.z) | ((unsigned)f2bfu(v.w) << 16);
        ((uint2*)dp)[j] = o;
    }
}

// ---------------------------------------------------------------------------
// Batched bf16 MFMA GEMM over blockIdx.z, 2-deep pipelined double-buffer with
// counted vmcnt (T3/T4): per K-step {wait vmcnt(SOPS); barrier; ds_read;
// lgkmcnt(0); barrier; stage(t+2); MFMA}. Stages stay in flight across
// barriers; vmcnt only drains at the tail.
// BM=128, BN=NF*32 (NF=4 or 2), BK=64, 256 thr (4 waves).
// EP: 1 relu->bf16 | 2 X(bf16)*sigmoid->bf16 | 4 bias->f32 |
//     7 per-z proj: z0 bias*0.125->bf16, z1 (.)*(mem*Wmm+bmm)->bf16,
//                   z2 same + transposed store vt[b][h][d][n]
// ---------------------------------------------------------------------------
struct GB {
    const ushort* A[3]; const ushort* W[3];
    const float* bias[3]; void* C[3]; const ushort* X[3];
};

template <int EP, int NF>
__global__ __launch_bounds__(256) void gemm_bf16(
    GB gb, int M, int N, int K,
    const float* __restrict__ mem, const float* __restrict__ Wmm,
    const float* __restrict__ bmm)
{
    __shared__ __align__(16) ushort As[2][128 * 64];
    __shared__ __align__(16) ushort Bs[2][NF * 32 * 64];
    const int z = blockIdx.z;
    const ushort* A = gb.A[z];
    const ushort* W = gb.W[z];
    const float* bias = gb.bias[z];
    void* Cout = gb.C[z];
    const ushort* X = gb.X[z];

    const int tid = threadIdx.x;
    const int lane = tid & 63, w = tid >> 6;
    const int lc = lane & 15, lg = lane >> 4;
    const int m0 = blockIdx.x * 128, n0 = blockIdx.y * (NF * 32);
    const int wm = (w >> 1) * 64, wn = (w & 1) * (NF * 16);
    const int srow = lane >> 3, scol = 8 * ((lane & 7) ^ srow);
    const int swl = (lc & 7) << 3;

    f32x4 acc[4][NF];
    #pragma unroll
    for (int i = 0; i < 4; ++i)
        #pragma unroll
        for (int j = 0; j < NF; ++j)
            acc[i][j] = (f32x4){0.f, 0.f, 0.f, 0.f};

    // stage one 128x64 A-tile (+ NF*32 x 64 B-tile) into buffer `buf`
    auto stage = [&](int buf, int k0) {
        #pragma unroll
        for (int ci = 0; ci < 4; ++ci) {
            int c = w + ci * 4;
            gll16(&A[(size_t)(m0 + c * 8 + srow) * K + k0 + scol], &As[buf][c * 512]);
            if (c < NF * 4)
                gll16(&W[(size_t)(n0 + c * 8 + srow) * K + k0 + scol], &Bs[buf][c * 512]);
        }
    };

    stage(0, 0);
    stage(1, 64);                       // K >= 128 in all uses
    const int nt = K / 64;

    for (int t = 0; t < nt; ++t) {
        const int cur = t & 1;
        // wait for stage(t) (own ops): SOPS = 4 + NF ops newer (stage t+1)
        if (t < nt - 1) {
            if constexpr (NF == 4) asm volatile("s_waitcnt vmcnt(8)" ::: "memory");
            else                   asm volatile("s_waitcnt vmcnt(6)" ::: "memory");
        } else {
            asm volatile("s_waitcnt vmcnt(0)" ::: "memory");
        }
        __builtin_amdgcn_sched_barrier(0);
        __builtin_amdgcn_s_barrier();   // all waves' stage(t) complete

        bf16x8 af[4][2], bfr[NF][2];
        #pragma unroll
        for (int mi = 0; mi < 4; ++mi) {
            int row = wm + mi * 16 + lc;
            af[mi][0] = *(const bf16x8*)&As[cur][row * 64 + ((lg * 8) ^ swl)];
            af[mi][1] = *(const bf16x8*)&As[cur][row * 64 + ((32 + lg * 8) ^ swl)];
        }
        #pragma unroll
        for (int nj = 0; nj < NF; ++nj) {
            int row = wn + nj * 16 + lc;
            bfr[nj][0] = *(const bf16x8*)&Bs[cur][row * 64 + ((lg * 8) ^ swl)];
            bfr[nj][1] = *(const bf16x8*)&Bs[cur][row * 64 + ((32 + lg * 8) ^ swl)];
        }
        asm volatile("s_waitcnt lgkmcnt(0)" ::: "memory");
        __builtin_amdgcn_sched_barrier(0);
        __builtin_amdgcn_s_barrier();   // all waves done reading buf[cur]

        if (t + 2 < nt) stage(cur, (t + 2) * 64);   // overwrite is now safe

        #pragma unroll
        for (int mi = 0; mi < 4; ++mi)
            #pragma unroll
            for (int nj = 0; nj < NF; ++nj) {
                acc[mi][nj] = mfma16(af[mi][0], bfr[nj][0], acc[mi][nj]);
                acc[mi][nj] = mfma16(af[mi][1], bfr[nj][1], acc[mi][nj]);
            }
    }

    // epilogue: C row = m0+wm+mi*16+lg*4+r, col = n0+wn+nj*16+lc
    #pragma unroll
    for (int nj = 0; nj < NF; ++nj) {
        int e = n0 + wn + nj * 16 + lc;
        float bv = bias[e];
        float wmv = 0.f, bmv = 0.f;
        if (EP == 7) { wmv = Wmm[e]; bmv = bmm[e]; }
        #pragma unroll
        for (int mi = 0; mi < 4; ++mi) {
            int mbase = m0 + wm + mi * 16 + lg * 4;
            if (EP == 7 && z == 2) {
                ushort u[4];
                #pragma unroll
                for (int r = 0; r < 4; ++r) {
                    float v = (acc[mi][nj][r] + bv) * (mem[mbase + r] * wmv + bmv);
                    u[r] = f2bfu(v);
                }
                int bb = mbase >> 10, n = mbase & 1023;
                size_t off = ((size_t)(bb * HH + (e >> 6)) * 64 + (e & 63)) * NN + n;
                uint2 pk;
                pk.x = (unsigned)u[0] | ((unsigned)u[1] << 16);
                pk.y = (unsigned)u[2] | ((unsigned)u[3] << 16);
                *(uint2*)&((ushort*)Cout)[off] = pk;
            } else {
                #pragma unroll
                for (int r = 0; r < 4; ++r) {
                    int m = mbase + r;
                    float v = acc[mi][nj][r] + bv;
                    if (EP == 1) v = fmaxf(v, 0.f);
                    if (EP == 2) v = bfu2f(X[(size_t)m * N + e]) * (1.f / (1.f + __expf(-v)));
                    if (EP == 7) {
                        if (z == 0) v = v * 0.125f;
                        else        v = v * (mem[m] * wmv + bmv);
                    }
                    size_t off = (size_t)m * N + e;
                    if (EP == 4) ((float*)Cout)[off] = v;
                    else         ((ushort*)Cout)[off] = f2bfu(v);
                }
            }
        }
    }
}

// ---------------------------------------------------------------------------
// MFMA flash attention, barrier-free: K/V fragments are read DIRECTLY from
// global (L2-resident: 16 q-tile blocks share each (b,h)'s 256 KB of K/V).
// Only LDS use is the per-wave-private P buffer (disjoint rows per wave, DS
// FIFO ordering within a wave) -> zero __syncthreads in the whole kernel.
// S^T = K*Q^T so lane holds 4 consecutive k for one q (float4 aw/mask loads,
// scalar per-lane row sum). Max-free softmax (logits ~1e-2).
// ---------------------------------------------------------------------------
__global__ __launch_bounds__(256) void attn_mfma(
    const ushort* __restrict__ qp, const ushort* __restrict__ kp,
    const ushort* __restrict__ vt, const float* __restrict__ aw,
    const void* __restrict__ maskp, const int* __restrict__ mflags,
    ushort* __restrict__ ob)
{
    __shared__ __align__(16) ushort Ps[64 * 64];
    const int tid = threadIdx.x, lane = tid & 63, w = tid >> 6;
    const int lc = lane & 15, lg = lane >> 4;
    const int qt = blockIdx.x, bh = blockIdx.y;
    const int b = bh >> 4, h = bh & 15;
    const int q0 = qt * 64, wq = w * 16;
    const int mode = mflags[0] ? (mflags[1] ? 1 : 2) : 0;
    const int swl = (lc & 7) << 3;

    // Q fragments from global, loaded once (B-operand of S^T)
    const ushort* qrow = &qp[(size_t)(b * NN + q0 + wq + lc) * DM + h * 64];
    bf16x8 bq0 = *(const bf16x8*)&qrow[lg * 8];
    bf16x8 bq1 = *(const bf16x8*)&qrow[32 + lg * 8];

    f32x4 oacc[4];
    #pragma unroll
    for (int i = 0; i < 4; ++i) oacc[i] = (f32x4){0.f, 0.f, 0.f, 0.f};
    float psum = 0.f;
    const int q = q0 + wq + lc;
    const float* awrow = aw + ((size_t)bh * NN + q) * NN;
    const size_t mrowo = ((size_t)b * NN + q) * NN;

    for (int t = 0; t < 16; ++t) {
        const int k0 = t * 64;

        // aw + mask loads for this tile (consumed after QK^T; TLP hides)
        float4 awv[4];
        #pragma unroll
        for (int mi = 0; mi < 4; ++mi)
            awv[mi] = *(const float4*)&awrow[k0 + mi * 16 + lg * 4];
        int4 mvi[4]; unsigned mvb[4]; float4 mvf[4];
        if (mode == 0) {
            #pragma unroll
            for (int mi = 0; mi < 4; ++mi)
                mvi[mi] = *(const int4*)&((const int*)maskp)[mrowo + k0 + mi * 16 + lg * 4];
        } else if (mode == 1) {
            #pragma unroll
            for (int mi = 0; mi < 4; ++mi)
                mvb[mi] = *(const unsigned*)&((const unsigned char*)maskp)[mrowo + k0 + mi * 16 + lg * 4];
        } else {
            #pragma unroll
            for (int mi = 0; mi < 4; ++mi)
                mvf[mi] = *(const float4*)&((const float*)maskp)[mrowo + k0 + mi * 16 + lg * 4];
        }

        // S^T = K·Q^T, K fragments direct from global (L2)
        f32x4 sacc[4];
        #pragma unroll
        for (int mi = 0; mi < 4; ++mi) {
            const ushort* krow = &kp[(size_t)(b * NN + k0 + mi * 16 + lc) * DM + h * 64];
            bf16x8 a0 = *(const bf16x8*)&krow[lg * 8];
            bf16x8 a1 = *(const bf16x8*)&krow[32 + lg * 8];
            f32x4 s = (f32x4){0.f, 0.f, 0.f, 0.f};
            s = mfma16(a0, bq0, s);
            s = mfma16(a1, bq1, s);
            sacc[mi] = s;
        }

        // softmax numerator -> P (bf16, own q-rows; wave-private, DS FIFO)
        #pragma unroll
        for (int mi = 0; mi < 4; ++mi) {
            unsigned mk[4];
            if (mode == 0) {
                mk[0] = mvi[mi].x != 0; mk[1] = mvi[mi].y != 0;
                mk[2] = mvi[mi].z != 0; mk[3] = mvi[mi].w != 0;
            } else if (mode == 1) {
                mk[0] = mvb[mi] & 0xffu;         mk[1] = (mvb[mi] >> 8) & 0xffu;
                mk[2] = (mvb[mi] >> 16) & 0xffu; mk[3] = (mvb[mi] >> 24) & 0xffu;
            } else {
                mk[0] = mvf[mi].x != 0.f; mk[1] = mvf[mi].y != 0.f;
                mk[2] = mvf[mi].z != 0.f; mk[3] = mvf[mi].w != 0.f;
            }
            const float aww[4] = {awv[mi].x, awv[mi].y, awv[mi].z, awv[mi].w};
            float pv[4];
            #pragma unroll
            for (int r = 0; r < 4; ++r) {
                float sv = sacc[mi][r] * aww[r];
                pv[r] = mk[r] ? 0.f : __expf(sv);
                psum += pv[r];
            }
            uint2 pk;
            pk.x = (unsigned)f2bfu(pv[0]) | ((unsigned)f2bfu(pv[1]) << 16);
            pk.y = (unsigned)f2bfu(pv[2]) | ((unsigned)f2bfu(pv[3]) << 16);
            *(uint2*)&Ps[(wq + lc) * 64 + ((mi * 16 + lg * 4) ^ swl)] = pk;
        }

        // PV: out[q][d] += P[q][k] * V[k][d]; V^T fragments direct from global
        #pragma unroll
        for (int kk = 0; kk < 2; ++kk) {
            bf16x8 pa = *(const bf16x8*)&Ps[(wq + lc) * 64 + ((kk * 32 + lg * 8) ^ swl)];
            #pragma unroll
            for (int nj = 0; nj < 4; ++nj) {
                bf16x8 vb = *(const bf16x8*)&vt[((size_t)bh * 64 + nj * 16 + lc) * NN + k0 + kk * 32 + lg * 8];
                oacc[nj] = mfma16(pa, vb, oacc[nj]);
            }
        }
    }

    psum += __shfl_xor(psum, 16);
    psum += __shfl_xor(psum, 32);
    float inv = 1.0f / psum;
    float invr[4];
    #pragma unroll
    for (int r = 0; r < 4; ++r)
        invr[r] = __shfl(inv, (lane & 48) | (lg * 4 + r));

    #pragma unroll
    for (int nj = 0; nj < 4; ++nj)
        #pragma unroll
        for (int r = 0; r < 4; ++r) {
            int qq = q0 + wq + lg * 4 + r;
            float v = oacc[nj][r] * invr[r];
            ob[(size_t)(b * NN + qq) * DM + h * 64 + nj * 16 + lc] = f2bfu(v);
        }
}

// ---------------------------------------------------------------------------
extern "C" void kernel_launch(void* const* d_in, const int* in_sizes, int n_in,
                              void* d_out, int out_size, void* d_ws, size_t ws_size,
                              hipStream_t stream) {
    const float* xin_f[3] = {(const float*)d_in[0], (const float*)d_in[1], (const float*)d_in[2]};
    const void*  maskp   = d_in[3];
    const float* aw      = (const float*)d_in[4];
    const float* memv    = (const float*)d_in[5];
    const float* Wp_f[3] = {(const float*)d_in[6], (const float*)d_in[8], (const float*)d_in[10]};
    const float* bp[3]   = {(const float*)d_in[7], (const float*)d_in[9], (const float*)d_in[11]};
    const float* Wo_f  = (const float*)d_in[12];  const float* bo  = (const float*)d_in[13];
    const float* Wmm = (const float*)d_in[14];    const float* bmm = (const float*)d_in[15];
    const float* W1f[3] = {(const float*)d_in[16], (const float*)d_in[20], (const float*)d_in[24]};
    const float* b1a[3] = {(const float*)d_in[17], (const float*)d_in[21], (const float*)d_in[25]};
    const float* W2f[3] = {(const float*)d_in[18], (const float*)d_in[22], (const float*)d_in[26]};
    const float* b2a[3] = {(const float*)d_in[19], (const float*)d_in[23], (const float*)d_in[27]};

    char* p = (char*)d_ws;
    auto alloc = [&](size_t bytes) { char* r = p; p += (bytes + 255) & ~(size_t)255; return r; };
    int*    mflags = (int*)alloc(256);
    ushort* xbf[3]; for (int t = 0; t < 3; ++t) xbf[t] = (ushort*)alloc((size_t)TT * DM * 2);
    ushort* Wpb[3]; for (int t = 0; t < 3; ++t) Wpb[t] = (ushort*)alloc((size_t)DM * DM * 2);
    ushort* Wob  = (ushort*)alloc((size_t)DM * DM * 2);
    ushort* W1b[3]; for (int t = 0; t < 3; ++t) W1b[t] = (ushort*)alloc((size_t)HID * DM * 2);
    ushort* W2b[3]; for (int t = 0; t < 3; ++t) W2b[t] = (ushort*)alloc((size_t)DM * HID * 2);
    ushort* hbuf[3]; for (int t = 0; t < 3; ++t) hbuf[t] = (ushort*)alloc((size_t)TT * HID * 2);
    ushort* xg[3];  for (int t = 0; t < 3; ++t) xg[t] = (ushort*)alloc((size_t)TT * DM * 2);
    ushort* qpb  = (ushort*)alloc((size_t)TT * DM * 2);
    ushort* ksb  = (ushort*)alloc((size_t)TT * DM * 2);
    ushort* vtb  = (ushort*)alloc((size_t)TT * DM * 2);
    ushort* obuf = (ushort*)alloc((size_t)TT * DM * 2);

    hipMemsetAsync(mflags, 0, 8, stream);
    detect_mask_kernel<<<256, 256, 0, stream>>>((const uint4*)maskp,
                                                BB * NN * NN / 16, mflags);

    {
        CvtArgs<3> a;
        for (int t = 0; t < 3; ++t) { a.s[t] = xin_f[t]; a.d[t] = xbf[t]; }
        cvt_multi<3><<<2048, 256, 0, stream>>>(a, TT * DM / 4);
    }
    {
        CvtArgs<4> a;
        a.s[0] = Wp_f[0]; a.d[0] = Wpb[0];
        a.s[1] = Wp_f[1]; a.d[1] = Wpb[1];
        a.s[2] = Wp_f[2]; a.d[2] = Wpb[2];
        a.s[3] = Wo_f;    a.d[3] = Wob;
        cvt_multi<4><<<2048, 256, 0, stream>>>(a, DM * DM / 4);
    }
    {
        CvtArgs<6> a;
        for (int t = 0; t < 3; ++t) { a.s[t] = W1f[t]; a.d[t] = W1b[t]; }
        for (int t = 0; t < 3; ++t) { a.s[3 + t] = W2f[t]; a.d[3 + t] = W2b[t]; }
        cvt_multi<6><<<2048, 256, 0, stream>>>(a, HID * DM / 4);
    }

    const dim3 blk(256);
    GB g1 = {}, g2 = {}, g3 = {}, g4 = {};
    for (int t = 0; t < 3; ++t) {
        g1.A[t] = xbf[t];  g1.W[t] = W1b[t]; g1.bias[t] = b1a[t]; g1.C[t] = hbuf[t];
        g2.A[t] = hbuf[t]; g2.W[t] = W2b[t]; g2.bias[t] = b2a[t]; g2.C[t] = xg[t]; g2.X[t] = xbf[t];
        g3.A[t] = xg[t];   g3.W[t] = Wpb[t]; g3.bias[t] = bp[t];
    }
    g3.C[0] = qpb; g3.C[1] = ksb; g3.C[2] = vtb;
    g4.A[0] = obuf; g4.W[0] = Wob; g4.bias[0] = bo; g4.C[0] = d_out;

    // g1: N=512, BN=64 -> grid (32,8,3)=768 blocks, 48 KB LDS (3 blk/CU)
    gemm_bf16<1, 2><<<dim3(TT / 128, HID / 64, 3), blk, 0, stream>>>(g1, TT, HID, DM, nullptr, nullptr, nullptr);
    // g2: N=1024, BN=128 -> (32,8,3)=768 blocks
    gemm_bf16<2, 4><<<dim3(TT / 128, DM / 128, 3), blk, 0, stream>>>(g2, TT, DM, HID, nullptr, nullptr, nullptr);
    // g3: N=1024, BN=128 -> (32,8,3)=768 blocks
    gemm_bf16<7, 4><<<dim3(TT / 128, DM / 128, 3), blk, 0, stream>>>(g3, TT, DM, DM, memv, Wmm, bmm);

    attn_mfma<<<dim3(NN / 64, BB * HH), blk, 0, stream>>>(qpb, ksb, vtb, aw,
                                                          maskp, mflags, obuf);

    // g4: N=1024, BN=64 -> (32,16,1)=512 blocks, 48 KB LDS
    gemm_bf16<4, 2><<<dim3(TT / 128, DM / 64, 1), blk, 0, stream>>>(g4, TT, DM, DM, nullptr, nullptr, nullptr);
}

// Round 6
// 269.717 us; speedup vs baseline: 1.4710x; 1.4710x over previous
//
#include <hip/hip_runtime.h>
#include <hip/hip_bf16.h>

#define BB    4
#define NN    1024
#define DM    1024
#define HH    16
#define HID   512
#define TT    (BB * NN)

typedef __attribute__((ext_vector_type(8))) short bf16x8;
typedef __attribute__((ext_vector_type(4))) float f32x4;

__device__ __forceinline__ ushort f2bfu(float f) {
    __hip_bfloat16 h = __float2bfloat16(f);
    return __builtin_bit_cast(ushort, h);
}

__device__ __forceinline__ float bfu2f(ushort u) {
    __hip_bfloat16 h = __builtin_bit_cast(__hip_bfloat16, u);
    return __bfloat162float(h);
}

__device__ __forceinline__ f32x4 mfma16(bf16x8 a, bf16x8 b, f32x4 c) {
    return __builtin_amdgcn_mfma_f32_16x16x32_bf16(a, b, c, 0, 0, 0);
}

// async 16B/lane global->LDS; lds dest = wave-uniform base + lane*16
__device__ __forceinline__ void gll16(const void* g, void* l) {
    __builtin_amdgcn_global_load_lds(
        (const __attribute__((address_space(1))) unsigned int*)g,
        (__attribute__((address_space(3))) unsigned int*)l, 16, 0, 0);
}

// ---------------------------------------------------------------------------
__global__ void detect_mask_kernel(const uint4* __restrict__ m,
                                   int n16, int* __restrict__ flags) {
    int stride = blockDim.x * gridDim.x;
    unsigned hi = 0, lo = 0;
    for (int i = blockIdx.x * blockDim.x + threadIdx.x; i < n16; i += stride) {
        uint4 v = m[i];
        unsigned o = v.x | v.y | v.z | v.w;
        lo |= o & 0xFFu;
        hi |= o & 0xFFFFFF00u;
    }
    if (hi) atomicOr(&flags[0], 1);
    if (lo) atomicOr(&flags[1], 1);
}

// ---------------------------------------------------------------------------
template <int NS>
struct CvtArgs { const float* s[NS]; ushort* d[NS]; };

template <int NS>
__global__ __launch_bounds__(256) void cvt_multi(CvtArgs<NS> a, int n4) {
    int total = n4 * NS;
    int stride = blockDim.x * gridDim.x;
    for (int i = blockIdx.x * blockDim.x + threadIdx.x; i < total; i += stride) {
        const float* sp = a.s[0];
        ushort* dp = a.d[0];
        #pragma unroll
        for (int k = 1; k < NS; ++k) {
            bool ge = i >= k * n4;
            sp = ge ? a.s[k] : sp;
            dp = ge ? a.d[k] : dp;
        }
        int j = i % n4;
        float4 v = ((const float4*)sp)[j];
        uint2 o;
        o.x = (unsigned)f2bfu(v.x) | ((unsigned)f2bfu(v.y) << 16);
        o.y = (unsigned)f2bfu(v.z) | ((unsigned)f2bfu(v.w) << 16);
        ((uint2*)dp)[j] = o;
    }
}

// ---------------------------------------------------------------------------
// Batched bf16 MFMA GEMM over blockIdx.z, 2-deep pipeline, counted vmcnt.
// (unchanged from R5 — per-K-step: wait vmcnt(own); barrier; ds_read;
//  lgkmcnt(0); barrier; stage(t+2); MFMA)
// ---------------------------------------------------------------------------
struct GB {
    const ushort* A[3]; const ushort* W[3];
    const float* bias[3]; void* C[3]; const ushort* X[3];
};

template <int EP, int NF>
__global__ __launch_bounds__(256) void gemm_bf16(
    GB gb, int M, int N, int K,
    const float* __restrict__ mem, const float* __restrict__ Wmm,
    const float* __restrict__ bmm)
{
    __shared__ __align__(16) ushort As[2][128 * 64];
    __shared__ __align__(16) ushort Bs[2][NF * 32 * 64];
    const int z = blockIdx.z;
    const ushort* A = gb.A[z];
    const ushort* W = gb.W[z];
    const float* bias = gb.bias[z];
    void* Cout = gb.C[z];
    const ushort* X = gb.X[z];

    const int tid = threadIdx.x;
    const int lane = tid & 63, w = tid >> 6;
    const int lc = lane & 15, lg = lane >> 4;
    const int m0 = blockIdx.x * 128, n0 = blockIdx.y * (NF * 32);
    const int wm = (w >> 1) * 64, wn = (w & 1) * (NF * 16);
    const int srow = lane >> 3, scol = 8 * ((lane & 7) ^ srow);
    const int swl = (lc & 7) << 3;

    f32x4 acc[4][NF];
    #pragma unroll
    for (int i = 0; i < 4; ++i)
        #pragma unroll
        for (int j = 0; j < NF; ++j)
            acc[i][j] = (f32x4){0.f, 0.f, 0.f, 0.f};

    auto stage = [&](int buf, int k0) {
        #pragma unroll
        for (int ci = 0; ci < 4; ++ci) {
            int c = w + ci * 4;
            gll16(&A[(size_t)(m0 + c * 8 + srow) * K + k0 + scol], &As[buf][c * 512]);
            if (c < NF * 4)
                gll16(&W[(size_t)(n0 + c * 8 + srow) * K + k0 + scol], &Bs[buf][c * 512]);
        }
    };

    stage(0, 0);
    stage(1, 64);
    const int nt = K / 64;

    for (int t = 0; t < nt; ++t) {
        const int cur = t & 1;
        if (t < nt - 1) {
            if constexpr (NF == 4) asm volatile("s_waitcnt vmcnt(8)" ::: "memory");
            else                   asm volatile("s_waitcnt vmcnt(6)" ::: "memory");
        } else {
            asm volatile("s_waitcnt vmcnt(0)" ::: "memory");
        }
        __builtin_amdgcn_sched_barrier(0);
        __builtin_amdgcn_s_barrier();

        bf16x8 af[4][2], bfr[NF][2];
        #pragma unroll
        for (int mi = 0; mi < 4; ++mi) {
            int row = wm + mi * 16 + lc;
            af[mi][0] = *(const bf16x8*)&As[cur][row * 64 + ((lg * 8) ^ swl)];
            af[mi][1] = *(const bf16x8*)&As[cur][row * 64 + ((32 + lg * 8) ^ swl)];
        }
        #pragma unroll
        for (int nj = 0; nj < NF; ++nj) {
            int row = wn + nj * 16 + lc;
            bfr[nj][0] = *(const bf16x8*)&Bs[cur][row * 64 + ((lg * 8) ^ swl)];
            bfr[nj][1] = *(const bf16x8*)&Bs[cur][row * 64 + ((32 + lg * 8) ^ swl)];
        }
        asm volatile("s_waitcnt lgkmcnt(0)" ::: "memory");
        __builtin_amdgcn_sched_barrier(0);
        __builtin_amdgcn_s_barrier();

        if (t + 2 < nt) stage(cur, (t + 2) * 64);

        #pragma unroll
        for (int mi = 0; mi < 4; ++mi)
            #pragma unroll
            for (int nj = 0; nj < NF; ++nj) {
                acc[mi][nj] = mfma16(af[mi][0], bfr[nj][0], acc[mi][nj]);
                acc[mi][nj] = mfma16(af[mi][1], bfr[nj][1], acc[mi][nj]);
            }
    }

    #pragma unroll
    for (int nj = 0; nj < NF; ++nj) {
        int e = n0 + wn + nj * 16 + lc;
        float bv = bias[e];
        float wmv = 0.f, bmv = 0.f;
        if (EP == 7) { wmv = Wmm[e]; bmv = bmm[e]; }
        #pragma unroll
        for (int mi = 0; mi < 4; ++mi) {
            int mbase = m0 + wm + mi * 16 + lg * 4;
            if (EP == 7 && z == 2) {
                ushort u[4];
                #pragma unroll
                for (int r = 0; r < 4; ++r) {
                    float v = (acc[mi][nj][r] + bv) * (mem[mbase + r] * wmv + bmv);
                    u[r] = f2bfu(v);
                }
                int bb = mbase >> 10, n = mbase & 1023;
                size_t off = ((size_t)(bb * HH + (e >> 6)) * 64 + (e & 63)) * NN + n;
                uint2 pk;
                pk.x = (unsigned)u[0] | ((unsigned)u[1] << 16);
                pk.y = (unsigned)u[2] | ((unsigned)u[3] << 16);
                *(uint2*)&((ushort*)Cout)[off] = pk;
            } else {
                #pragma unroll
                for (int r = 0; r < 4; ++r) {
                    int m = mbase + r;
                    float v = acc[mi][nj][r] + bv;
                    if (EP == 1) v = fmaxf(v, 0.f);
                    if (EP == 2) v = bfu2f(X[(size_t)m * N + e]) * (1.f / (1.f + __expf(-v)));
                    if (EP == 7) {
                        if (z == 0) v = v * 0.125f;
                        else        v = v * (mem[m] * wmv + bmv);
                    }
                    size_t off = (size_t)m * N + e;
                    if (EP == 4) ((float*)Cout)[off] = v;
                    else         ((ushort*)Cout)[off] = f2bfu(v);
                }
            }
        }
    }
}

// ---------------------------------------------------------------------------
// MFMA flash attention v3: double-buffered global_load_lds K/V staging with
// counted vmcnt + raw s_barrier (1 barrier/iter, never drains in-loop), and
// aw/mask prefetched one tile ahead into ping-pong register sets (loop
// unrolled by 2 -> all indices static). XCD chunk swizzle: 16 q-tile blocks
// sharing a (b,h)'s 256 KB K/V land on one XCD's L2.
// Per-wave VMEM order per iter: [4 gll16][8 aw/mask loads] | body |
// vmcnt(8) (leaves the 8 prefetch loads in flight), s_barrier.
// ---------------------------------------------------------------------------
__global__ __launch_bounds__(256) void attn_mfma(
    const ushort* __restrict__ qp, const ushort* __restrict__ kp,
    const ushort* __restrict__ vt, const float* __restrict__ aw,
    const void* __restrict__ maskp, const int* __restrict__ mflags,
    ushort* __restrict__ ob)
{
    __shared__ __align__(16) ushort Ks[2][64 * 64];
    __shared__ __align__(16) ushort Vs[2][64 * 64];
    __shared__ __align__(16) ushort Ps[64 * 64];
    const int tid = threadIdx.x, lane = tid & 63, w = tid >> 6;
    const int lc = lane & 15, lg = lane >> 4;
    const int bid = blockIdx.x;
    const int swz = (bid & 7) * 128 + (bid >> 3);   // XCD chunking (1024%8==0)
    const int qt = swz & 15, bh = swz >> 4;
    const int b = bh >> 4, h = bh & 15;
    const int q0 = qt * 64, wq = w * 16;
    const int mode = mflags[0] ? (mflags[1] ? 1 : 2) : 0;
    const int srow = lane >> 3, scol = 8 * ((lane & 7) ^ srow);
    const int swl = (lc & 7) << 3;

    // Q fragments from global, loaded once (B-operand of S^T)
    const ushort* qrow = &qp[(size_t)(b * NN + q0 + wq + lc) * DM + h * 64];
    bf16x8 bq0 = *(const bf16x8*)&qrow[lg * 8];
    bf16x8 bq1 = *(const bf16x8*)&qrow[32 + lg * 8];

    f32x4 oacc[4];
    #pragma unroll
    for (int i = 0; i < 4; ++i) oacc[i] = (f32x4){0.f, 0.f, 0.f, 0.f};
    float psum = 0.f;
    const int q = q0 + wq + lc;
    const float* awrow = aw + ((size_t)bh * NN + q) * NN;
    const size_t mrowo = ((size_t)b * NN + q) * NN;   // mask row, element units

    float4 awA[4], awB[4];
    uint4 mk4A[4], mk4B[4];
    unsigned mk1A[4], mk1B[4];

    // prologue: stage tile 0, load aw/mask tile 0 into set A, drain, barrier
    #pragma unroll
    for (int ci = 0; ci < 2; ++ci) {
        int c = w + ci * 4;
        gll16(&kp[(size_t)(b * NN + c * 8 + srow) * DM + h * 64 + scol], &Ks[0][c * 512]);
        gll16(&vt[((size_t)bh * 64 + c * 8 + srow) * NN + 0 + scol], &Vs[0][c * 512]);
    }
    #pragma unroll
    for (int mi = 0; mi < 4; ++mi)
        awA[mi] = *(const float4*)&awrow[mi * 16 + lg * 4];
    if (mode == 1) {
        #pragma unroll
        for (int mi = 0; mi < 4; ++mi)
            mk1A[mi] = *(const unsigned*)&((const unsigned char*)maskp)[mrowo + mi * 16 + lg * 4];
    } else {
        #pragma unroll
        for (int mi = 0; mi < 4; ++mi)
            mk4A[mi] = *(const uint4*)((const char*)maskp + 4 * (mrowo + mi * 16 + lg * 4));
    }
    asm volatile("s_waitcnt vmcnt(0)" ::: "memory");
    __builtin_amdgcn_sched_barrier(0);
    __builtin_amdgcn_s_barrier();

#define ATTN_BODY(T, AWC, MK4C, MK1C, AWN, MK4N, MK1N)                          \
    {                                                                           \
        const int cur = (T) & 1;                                                \
        if ((T) < 15) {                                                         \
            const int kn = ((T) + 1) * 64;                                      \
            _Pragma("unroll")                                                   \
            for (int ci = 0; ci < 2; ++ci) {                                    \
                int c = w + ci * 4;                                             \
                gll16(&kp[(size_t)(b * NN + kn + c * 8 + srow) * DM + h * 64 + scol], \
                      &Ks[cur ^ 1][c * 512]);                                   \
                gll16(&vt[((size_t)bh * 64 + c * 8 + srow) * NN + kn + scol],   \
                      &Vs[cur ^ 1][c * 512]);                                   \
            }                                                                   \
            __builtin_amdgcn_sched_barrier(0);                                  \
            _Pragma("unroll")                                                   \
            for (int mi = 0; mi < 4; ++mi)                                      \
                AWN[mi] = *(const float4*)&awrow[kn + mi * 16 + lg * 4];        \
            if (mode == 1) {                                                    \
                _Pragma("unroll")                                               \
                for (int mi = 0; mi < 4; ++mi)                                  \
                    MK1N[mi] = *(const unsigned*)&((const unsigned char*)maskp) \
                                   [mrowo + kn + mi * 16 + lg * 4];             \
            } else {                                                            \
                _Pragma("unroll")                                               \
                for (int mi = 0; mi < 4; ++mi)                                  \
                    MK4N[mi] = *(const uint4*)((const char*)maskp +             \
                                   4 * (mrowo + kn + mi * 16 + lg * 4));        \
            }                                                                   \
            __builtin_amdgcn_sched_barrier(0);                                  \
        }                                                                       \
        /* S^T = K·Q^T */                                                       \
        f32x4 sacc[4];                                                          \
        __builtin_amdgcn_s_setprio(1);                                          \
        _Pragma("unroll")                                                       \
        for (int mi = 0; mi < 4; ++mi) {                                        \
            int krow = mi * 16 + lc;                                            \
            bf16x8 a0 = *(const bf16x8*)&Ks[cur][krow * 64 + ((lg * 8) ^ swl)]; \
            bf16x8 a1 = *(const bf16x8*)&Ks[cur][krow * 64 + ((32 + lg * 8) ^ swl)]; \
            f32x4 s = (f32x4){0.f, 0.f, 0.f, 0.f};                              \
            s = mfma16(a0, bq0, s);                                             \
            s = mfma16(a1, bq1, s);                                             \
            sacc[mi] = s;                                                       \
        }                                                                       \
        __builtin_amdgcn_s_setprio(0);                                          \
        /* softmax numerator -> P (bf16, own q-rows) */                         \
        _Pragma("unroll")                                                       \
        for (int mi = 0; mi < 4; ++mi) {                                        \
            unsigned mk[4];                                                     \
            if (mode == 1) {                                                    \
                mk[0] = MK1C[mi] & 0xffu;         mk[1] = (MK1C[mi] >> 8) & 0xffu;  \
                mk[2] = (MK1C[mi] >> 16) & 0xffu; mk[3] = (MK1C[mi] >> 24) & 0xffu; \
            } else if (mode == 0) {                                             \
                mk[0] = MK4C[mi].x; mk[1] = MK4C[mi].y;                         \
                mk[2] = MK4C[mi].z; mk[3] = MK4C[mi].w;                         \
            } else {                                                            \
                mk[0] = MK4C[mi].x != 0; mk[1] = MK4C[mi].y != 0;               \
                mk[2] = MK4C[mi].z != 0; mk[3] = MK4C[mi].w != 0;               \
            }                                                                   \
            const float aww[4] = {AWC[mi].x, AWC[mi].y, AWC[mi].z, AWC[mi].w};  \
            float pv[4];                                                        \
            _Pragma("unroll")                                                   \
            for (int r = 0; r < 4; ++r) {                                       \
                float sv = sacc[mi][r] * aww[r];                                \
                pv[r] = mk[r] ? 0.f : __expf(sv);                               \
                psum += pv[r];                                                  \
            }                                                                   \
            uint2 pk;                                                           \
            pk.x = (unsigned)f2bfu(pv[0]) | ((unsigned)f2bfu(pv[1]) << 16);     \
            pk.y = (unsigned)f2bfu(pv[2]) | ((unsigned)f2bfu(pv[3]) << 16);     \
            *(uint2*)&Ps[(wq + lc) * 64 + ((mi * 16 + lg * 4) ^ swl)] = pk;     \
        }                                                                       \
        /* PV */                                                                \
        __builtin_amdgcn_s_setprio(1);                                          \
        _Pragma("unroll")                                                       \
        for (int kk = 0; kk < 2; ++kk) {                                        \
            bf16x8 pa = *(const bf16x8*)&Ps[(wq + lc) * 64 + ((kk * 32 + lg * 8) ^ swl)]; \
            _Pragma("unroll")                                                   \
            for (int nj = 0; nj < 4; ++nj) {                                    \
                bf16x8 vb = *(const bf16x8*)&Vs[cur][(nj * 16 + lc) * 64 + ((kk * 32 + lg * 8) ^ swl)]; \
                oacc[nj] = mfma16(pa, vb, oacc[nj]);                            \
            }                                                                   \
        }                                                                       \
        __builtin_amdgcn_s_setprio(0);                                          \
        if ((T) < 15) {                                                         \
            asm volatile("s_waitcnt vmcnt(8)" ::: "memory");                    \
            __builtin_amdgcn_sched_barrier(0);                                  \
            __builtin_amdgcn_s_barrier();                                       \
        }                                                                       \
    }

    for (int tt = 0; tt < 8; ++tt) {
        const int t0 = tt * 2, t1 = tt * 2 + 1;
        ATTN_BODY(t0, awA, mk4A, mk1A, awB, mk4B, mk1B);
        ATTN_BODY(t1, awB, mk4B, mk1B, awA, mk4A, mk1A);
    }
#undef ATTN_BODY

    psum += __shfl_xor(psum, 16);
    psum += __shfl_xor(psum, 32);
    float inv = 1.0f / psum;
    float invr[4];
    #pragma unroll
    for (int r = 0; r < 4; ++r)
        invr[r] = __shfl(inv, (lane & 48) | (lg * 4 + r));

    #pragma unroll
    for (int nj = 0; nj < 4; ++nj)
        #pragma unroll
        for (int r = 0; r < 4; ++r) {
            int qq = q0 + wq + lg * 4 + r;
            float v = oacc[nj][r] * invr[r];
            ob[(size_t)(b * NN + qq) * DM + h * 64 + nj * 16 + lc] = f2bfu(v);
        }
}

// ---------------------------------------------------------------------------
extern "C" void kernel_launch(void* const* d_in, const int* in_sizes, int n_in,
                              void* d_out, int out_size, void* d_ws, size_t ws_size,
                              hipStream_t stream) {
    const float* xin_f[3] = {(const float*)d_in[0], (const float*)d_in[1], (const float*)d_in[2]};
    const void*  maskp   = d_in[3];
    const float* aw      = (const float*)d_in[4];
    const float* memv    = (const float*)d_in[5];
    const float* Wp_f[3] = {(const float*)d_in[6], (const float*)d_in[8], (const float*)d_in[10]};
    const float* bp[3]   = {(const float*)d_in[7], (const float*)d_in[9], (const float*)d_in[11]};
    const float* Wo_f  = (const float*)d_in[12];  const float* bo  = (const float*)d_in[13];
    const float* Wmm = (const float*)d_in[14];    const float* bmm = (const float*)d_in[15];
    const float* W1f[3] = {(const float*)d_in[16], (const float*)d_in[20], (const float*)d_in[24]};
    const float* b1a[3] = {(const float*)d_in[17], (const float*)d_in[21], (const float*)d_in[25]};
    const float* W2f[3] = {(const float*)d_in[18], (const float*)d_in[22], (const float*)d_in[26]};
    const float* b2a[3] = {(const float*)d_in[19], (const float*)d_in[23], (const float*)d_in[27]};

    char* p = (char*)d_ws;
    auto alloc = [&](size_t bytes) { char* r = p; p += (bytes + 255) & ~(size_t)255; return r; };
    int*    mflags = (int*)alloc(256);
    ushort* xbf[3]; for (int t = 0; t < 3; ++t) xbf[t] = (ushort*)alloc((size_t)TT * DM * 2);
    ushort* Wpb[3]; for (int t = 0; t < 3; ++t) Wpb[t] = (ushort*)alloc((size_t)DM * DM * 2);
    ushort* Wob  = (ushort*)alloc((size_t)DM * DM * 2);
    ushort* W1b[3]; for (int t = 0; t < 3; ++t) W1b[t] = (ushort*)alloc((size_t)HID * DM * 2);
    ushort* W2b[3]; for (int t = 0; t < 3; ++t) W2b[t] = (ushort*)alloc((size_t)DM * HID * 2);
    ushort* hbuf[3]; for (int t = 0; t < 3; ++t) hbuf[t] = (ushort*)alloc((size_t)TT * HID * 2);
    ushort* xg[3];  for (int t = 0; t < 3; ++t) xg[t] = (ushort*)alloc((size_t)TT * DM * 2);
    ushort* qpb  = (ushort*)alloc((size_t)TT * DM * 2);
    ushort* ksb  = (ushort*)alloc((size_t)TT * DM * 2);
    ushort* vtb  = (ushort*)alloc((size_t)TT * DM * 2);
    ushort* obuf = (ushort*)alloc((size_t)TT * DM * 2);

    hipMemsetAsync(mflags, 0, 8, stream);
    detect_mask_kernel<<<256, 256, 0, stream>>>((const uint4*)maskp,
                                                BB * NN * NN / 16, mflags);

    {
        CvtArgs<3> a;
        for (int t = 0; t < 3; ++t) { a.s[t] = xin_f[t]; a.d[t] = xbf[t]; }
        cvt_multi<3><<<2048, 256, 0, stream>>>(a, TT * DM / 4);
    }
    {
        CvtArgs<4> a;
        a.s[0] = Wp_f[0]; a.d[0] = Wpb[0];
        a.s[1] = Wp_f[1]; a.d[1] = Wpb[1];
        a.s[2] = Wp_f[2]; a.d[2] = Wpb[2];
        a.s[3] = Wo_f;    a.d[3] = Wob;
        cvt_multi<4><<<2048, 256, 0, stream>>>(a, DM * DM / 4);
    }
    {
        CvtArgs<6> a;
        for (int t = 0; t < 3; ++t) { a.s[t] = W1f[t]; a.d[t] = W1b[t]; }
        for (int t = 0; t < 3; ++t) { a.s[3 + t] = W2f[t]; a.d[3 + t] = W2b[t]; }
        cvt_multi<6><<<2048, 256, 0, stream>>>(a, HID * DM / 4);
    }

    const dim3 blk(256);
    GB g1 = {}, g2 = {}, g3 = {}, g4 = {};
    for (int t = 0; t < 3; ++t) {
        g1.A[t] = xbf[t];  g1.W[t] = W1b[t]; g1.bias[t] = b1a[t]; g1.C[t] = hbuf[t];
        g2.A[t] = hbuf[t]; g2.W[t] = W2b[t]; g2.bias[t] = b2a[t]; g2.C[t] = xg[t]; g2.X[t] = xbf[t];
        g3.A[t] = xg[t];   g3.W[t] = Wpb[t]; g3.bias[t] = bp[t];
    }
    g3.C[0] = qpb; g3.C[1] = ksb; g3.C[2] = vtb;
    g4.A[0] = obuf; g4.W[0] = Wob; g4.bias[0] = bo; g4.C[0] = d_out;

    gemm_bf16<1, 2><<<dim3(TT / 128, HID / 64, 3), blk, 0, stream>>>(g1, TT, HID, DM, nullptr, nullptr, nullptr);
    gemm_bf16<2, 4><<<dim3(TT / 128, DM / 128, 3), blk, 0, stream>>>(g2, TT, DM, HID, nullptr, nullptr, nullptr);
    gemm_bf16<7, 4><<<dim3(TT / 128, DM / 128, 3), blk, 0, stream>>>(g3, TT, DM, DM, memv, Wmm, bmm);

    attn_mfma<<<dim3(NN / 16 * (BB * HH) / 4), blk, 0, stream>>>(qpb, ksb, vtb, aw,
                                                                 maskp, mflags, obuf);

    gemm_bf16<4, 2><<<dim3(TT / 128, DM / 64, 1), blk, 0, stream>>>(g4, TT, DM, DM, nullptr, nullptr, nullptr);
}

// Round 10
// 260.891 us; speedup vs baseline: 1.5208x; 1.0338x over previous
//
#include <hip/hip_runtime.h>
#include <hip/hip_bf16.h>

#define BB    4
#define NN    1024
#define DM    1024
#define HH    16
#define HID   512
#define TT    (BB * NN)

typedef __attribute__((ext_vector_type(8))) short bf16x8;
typedef __attribute__((ext_vector_type(4))) float f32x4;

__device__ __forceinline__ ushort f2bfu(float f) {
    __hip_bfloat16 h = __float2bfloat16(f);
    return __builtin_bit_cast(ushort, h);
}

__device__ __forceinline__ float bfu2f(ushort u) {
    __hip_bfloat16 h = __builtin_bit_cast(__hip_bfloat16, u);
    return __bfloat162float(h);
}

__device__ __forceinline__ f32x4 mfma16(bf16x8 a, bf16x8 b, f32x4 c) {
    return __builtin_amdgcn_mfma_f32_16x16x32_bf16(a, b, c, 0, 0, 0);
}

// async 16B/lane global->LDS; lds dest = wave-uniform base + lane*16
__device__ __forceinline__ void gll16(const void* g, void* l) {
    __builtin_amdgcn_global_load_lds(
        (const __attribute__((address_space(1))) unsigned int*)g,
        (__attribute__((address_space(3))) unsigned int*)l, 16, 0, 0);
}

// ---------------------------------------------------------------------------
__global__ void detect_mask_kernel(const uint4* __restrict__ m,
                                   int n16, int* __restrict__ flags) {
    int stride = blockDim.x * gridDim.x;
    unsigned hi = 0, lo = 0;
    for (int i = blockIdx.x * blockDim.x + threadIdx.x; i < n16; i += stride) {
        uint4 v = m[i];
        unsigned o = v.x | v.y | v.z | v.w;
        lo |= o & 0xFFu;
        hi |= o & 0xFFFFFF00u;
    }
    if (hi) atomicOr(&flags[0], 1);
    if (lo) atomicOr(&flags[1], 1);
}

// ---------------------------------------------------------------------------
// Single-dispatch f32->bf16 convert over 13 unequal segments.
// ---------------------------------------------------------------------------
#define NSEG 13
struct CvtAll { const float* s[NSEG]; ushort* d[NSEG]; int bound[NSEG]; };

__global__ __launch_bounds__(256) void cvt_all(CvtAll a, int total) {
    int stride = blockDim.x * gridDim.x;
    for (int i = blockIdx.x * blockDim.x + threadIdx.x; i < total; i += stride) {
        const float* sp = a.s[0];
        ushort* dp = a.d[0];
        int base = 0;
        #pragma unroll
        for (int k = 1; k < NSEG; ++k) {
            bool ge = i >= a.bound[k - 1];
            sp = ge ? a.s[k] : sp;
            dp = ge ? a.d[k] : dp;
            base = ge ? a.bound[k - 1] : base;
        }
        int j = i - base;
        float4 v = ((const float4*)sp)[j];
        uint2 o;
        o.x = (unsigned)f2bfu(v.x) | ((unsigned)f2bfu(v.y) << 16);
        o.y = (unsigned)f2bfu(v.z) | ((unsigned)f2bfu(v.w) << 16);
        ((uint2*)dp)[j] = o;
    }
}

// ---------------------------------------------------------------------------
// Batched bf16 MFMA GEMM over blockIdx.z, 2-deep pipeline, counted vmcnt.
// All counted VMEM ops are HOMOGENEOUS global_load_lds (in-order, safe).
// BM=128, BN=NF*32, BK=64, 256 thr. NF=2 everywhere (48 KB LDS, 3 blk/CU).
// ---------------------------------------------------------------------------
struct GB {
    const ushort* A[3]; const ushort* W[3];
    const float* bias[3]; void* C[3]; const ushort* X[3];
};

template <int EP, int NF>
__global__ __launch_bounds__(256) void gemm_bf16(
    GB gb, int M, int N, int K,
    const float* __restrict__ mem, const float* __restrict__ Wmm,
    const float* __restrict__ bmm)
{
    __shared__ __align__(16) ushort As[2][128 * 64];
    __shared__ __align__(16) ushort Bs[2][NF * 32 * 64];
    const int z = blockIdx.z;
    const ushort* A = gb.A[z];
    const ushort* W = gb.W[z];
    const float* bias = gb.bias[z];
    void* Cout = gb.C[z];
    const ushort* X = gb.X[z];

    const int tid = threadIdx.x;
    const int lane = tid & 63, w = tid >> 6;
    const int lc = lane & 15, lg = lane >> 4;
    const int m0 = blockIdx.x * 128, n0 = blockIdx.y * (NF * 32);
    const int wm = (w >> 1) * 64, wn = (w & 1) * (NF * 16);
    const int srow = lane >> 3, scol = 8 * ((lane & 7) ^ srow);
    const int swl = (lc & 7) << 3;

    f32x4 acc[4][NF];
    #pragma unroll
    for (int i = 0; i < 4; ++i)
        #pragma unroll
        for (int j = 0; j < NF; ++j)
            acc[i][j] = (f32x4){0.f, 0.f, 0.f, 0.f};

    auto stage = [&](int buf, int k0) {
        #pragma unroll
        for (int ci = 0; ci < 4; ++ci) {
            int c = w + ci * 4;
            gll16(&A[(size_t)(m0 + c * 8 + srow) * K + k0 + scol], &As[buf][c * 512]);
            if (c < NF * 4)
                gll16(&W[(size_t)(n0 + c * 8 + srow) * K + k0 + scol], &Bs[buf][c * 512]);
        }
    };

    stage(0, 0);
    stage(1, 64);
    const int nt = K / 64;

    for (int t = 0; t < nt; ++t) {
        const int cur = t & 1;
        if (t < nt - 1) {
            if constexpr (NF == 4) asm volatile("s_waitcnt vmcnt(8)" ::: "memory");
            else                   asm volatile("s_waitcnt vmcnt(6)" ::: "memory");
        } else {
            asm volatile("s_waitcnt vmcnt(0)" ::: "memory");
        }
        __builtin_amdgcn_sched_barrier(0);
        __builtin_amdgcn_s_barrier();

        bf16x8 af[4][2], bfr[NF][2];
        #pragma unroll
        for (int mi = 0; mi < 4; ++mi) {
            int row = wm + mi * 16 + lc;
            af[mi][0] = *(const bf16x8*)&As[cur][row * 64 + ((lg * 8) ^ swl)];
            af[mi][1] = *(const bf16x8*)&As[cur][row * 64 + ((32 + lg * 8) ^ swl)];
        }
        #pragma unroll
        for (int nj = 0; nj < NF; ++nj) {
            int row = wn + nj * 16 + lc;
            bfr[nj][0] = *(const bf16x8*)&Bs[cur][row * 64 + ((lg * 8) ^ swl)];
            bfr[nj][1] = *(const bf16x8*)&Bs[cur][row * 64 + ((32 + lg * 8) ^ swl)];
        }
        asm volatile("s_waitcnt lgkmcnt(0)" ::: "memory");
        __builtin_amdgcn_sched_barrier(0);
        __builtin_amdgcn_s_barrier();

        if (t + 2 < nt) stage(cur, (t + 2) * 64);

        #pragma unroll
        for (int mi = 0; mi < 4; ++mi)
            #pragma unroll
            for (int nj = 0; nj < NF; ++nj) {
                acc[mi][nj] = mfma16(af[mi][0], bfr[nj][0], acc[mi][nj]);
                acc[mi][nj] = mfma16(af[mi][1], bfr[nj][1], acc[mi][nj]);
            }
    }

    #pragma unroll
    for (int nj = 0; nj < NF; ++nj) {
        int e = n0 + wn + nj * 16 + lc;
        float bv = bias[e];
        float wmv = 0.f, bmv = 0.f;
        if (EP == 7) { wmv = Wmm[e]; bmv = bmm[e]; }
        #pragma unroll
        for (int mi = 0; mi < 4; ++mi) {
            int mbase = m0 + wm + mi * 16 + lg * 4;
            if (EP == 7 && z == 2) {
                ushort u[4];
                #pragma unroll
                for (int r = 0; r < 4; ++r) {
                    float v = (acc[mi][nj][r] + bv) * (mem[mbase + r] * wmv + bmv);
                    u[r] = f2bfu(v);
                }
                int bb = mbase >> 10, n = mbase & 1023;
                size_t off = ((size_t)(bb * HH + (e >> 6)) * 64 + (e & 63)) * NN + n;
                uint2 pk;
                pk.x = (unsigned)u[0] | ((unsigned)u[1] << 16);
                pk.y = (unsigned)u[2] | ((unsigned)u[3] << 16);
                *(uint2*)&((ushort*)Cout)[off] = pk;
            } else {
                #pragma unroll
                for (int r = 0; r < 4; ++r) {
                    int m = mbase + r;
                    float v = acc[mi][nj][r] + bv;
                    if (EP == 1) v = fmaxf(v, 0.f);
                    if (EP == 2) v = bfu2f(X[(size_t)m * N + e]) * (1.f / (1.f + __expf(-v)));
                    if (EP == 7) {
                        if (z == 0) v = v * 0.125f;
                        else        v = v * (mem[m] * wmv + bmv);
                    }
                    size_t off = (size_t)m * N + e;
                    if (EP == 4) ((float*)Cout)[off] = v;
                    else         ((ushort*)Cout)[off] = f2bfu(v);
                }
            }
        }
    }
}

// ---------------------------------------------------------------------------
// MFMA flash attention — R6 structure verbatim (the last fully-passing
// attention), with ONE safety edit: the end-of-body wait is vmcnt(0) instead
// of the mixed-class counted vmcnt(8). All 12 VMEM ops per body issue at the
// body top, so the full drain waits on the same batch — ~zero extra cost.
// Single kernel, all mask modes (uniform branch). Double-buffered gll16 K/V,
// distance-1 aw/mask register prefetch (ping-pong sets, static indices),
// sched_barrier pins, setprio around MFMA, XCD chunk swizzle.
// ---------------------------------------------------------------------------
__global__ __launch_bounds__(256) void attn_mfma(
    const ushort* __restrict__ qp, const ushort* __restrict__ kp,
    const ushort* __restrict__ vt, const float* __restrict__ aw,
    const void* __restrict__ maskp, const int* __restrict__ mflags,
    ushort* __restrict__ ob)
{
    __shared__ __align__(16) ushort Ks[2][64 * 64];
    __shared__ __align__(16) ushort Vs[2][64 * 64];
    __shared__ __align__(16) ushort Ps[64 * 64];
    const int tid = threadIdx.x, lane = tid & 63, w = tid >> 6;
    const int lc = lane & 15, lg = lane >> 4;
    const int bid = blockIdx.x;
    const int swz = (bid & 7) * 128 + (bid >> 3);   // 1024 % 8 == 0: bijective
    const int qt = swz & 15, bh = swz >> 4;
    const int b = bh >> 4, h = bh & 15;
    const int q0 = qt * 64, wq = w * 16;
    const int mode = mflags[0] ? (mflags[1] ? 1 : 2) : 0;
    const int srow = lane >> 3, scol = 8 * ((lane & 7) ^ srow);
    const int swl = (lc & 7) << 3;

    // Q fragments from global, loaded once (B-operand of S^T)
    const ushort* qrow = &qp[(size_t)(b * NN + q0 + wq + lc) * DM + h * 64];
    bf16x8 bq0 = *(const bf16x8*)&qrow[lg * 8];
    bf16x8 bq1 = *(const bf16x8*)&qrow[32 + lg * 8];

    f32x4 oacc[4];
    #pragma unroll
    for (int i = 0; i < 4; ++i) oacc[i] = (f32x4){0.f, 0.f, 0.f, 0.f};
    float psum = 0.f;
    const int q = q0 + wq + lc;
    const float* awrow = aw + ((size_t)bh * NN + q) * NN;
    const size_t mrowo = ((size_t)b * NN + q) * NN;   // mask row, element units

    float4 awA[4], awB[4];
    uint4 mk4A[4], mk4B[4];
    unsigned mk1A[4], mk1B[4];

    // prologue: stage tile 0, load aw/mask tile 0 into set A, drain, barrier
    #pragma unroll
    for (int ci = 0; ci < 2; ++ci) {
        int c = w + ci * 4;
        gll16(&kp[(size_t)(b * NN + c * 8 + srow) * DM + h * 64 + scol], &Ks[0][c * 512]);
        gll16(&vt[((size_t)bh * 64 + c * 8 + srow) * NN + 0 + scol], &Vs[0][c * 512]);
    }
    #pragma unroll
    for (int mi = 0; mi < 4; ++mi)
        awA[mi] = *(const float4*)&awrow[mi * 16 + lg * 4];
    if (mode == 1) {
        #pragma unroll
        for (int mi = 0; mi < 4; ++mi)
            mk1A[mi] = *(const unsigned*)&((const unsigned char*)maskp)[mrowo + mi * 16 + lg * 4];
    } else {
        #pragma unroll
        for (int mi = 0; mi < 4; ++mi)
            mk4A[mi] = *(const uint4*)((const char*)maskp + 4 * (mrowo + mi * 16 + lg * 4));
    }
    asm volatile("s_waitcnt vmcnt(0)" ::: "memory");
    __builtin_amdgcn_sched_barrier(0);
    __builtin_amdgcn_s_barrier();

#define ATTN_BODY(T, AWC, MK4C, MK1C, AWN, MK4N, MK1N)                          \
    {                                                                           \
        const int cur = (T) & 1;                                                \
        if ((T) < 15) {                                                         \
            const int kn = ((T) + 1) * 64;                                      \
            _Pragma("unroll")                                                   \
            for (int ci = 0; ci < 2; ++ci) {                                    \
                int c = w + ci * 4;                                             \
                gll16(&kp[(size_t)(b * NN + kn + c * 8 + srow) * DM + h * 64 + scol], \
                      &Ks[cur ^ 1][c * 512]);                                   \
                gll16(&vt[((size_t)bh * 64 + c * 8 + srow) * NN + kn + scol],   \
                      &Vs[cur ^ 1][c * 512]);                                   \
            }                                                                   \
            __builtin_amdgcn_sched_barrier(0);                                  \
            _Pragma("unroll")                                                   \
            for (int mi = 0; mi < 4; ++mi)                                      \
                AWN[mi] = *(const float4*)&awrow[kn + mi * 16 + lg * 4];        \
            if (mode == 1) {                                                    \
                _Pragma("unroll")                                               \
                for (int mi = 0; mi < 4; ++mi)                                  \
                    MK1N[mi] = *(const unsigned*)&((const unsigned char*)maskp) \
                                   [mrowo + kn + mi * 16 + lg * 4];             \
            } else {                                                            \
                _Pragma("unroll")                                               \
                for (int mi = 0; mi < 4; ++mi)                                  \
                    MK4N[mi] = *(const uint4*)((const char*)maskp +             \
                                   4 * (mrowo + kn + mi * 16 + lg * 4));        \
            }                                                                   \
            __builtin_amdgcn_sched_barrier(0);                                  \
        }                                                                       \
        /* S^T = K·Q^T */                                                       \
        f32x4 sacc[4];                                                          \
        __builtin_amdgcn_s_setprio(1);                                          \
        _Pragma("unroll")                                                       \
        for (int mi = 0; mi < 4; ++mi) {                                        \
            int krow = mi * 16 + lc;                                            \
            bf16x8 a0 = *(const bf16x8*)&Ks[cur][krow * 64 + ((lg * 8) ^ swl)]; \
            bf16x8 a1 = *(const bf16x8*)&Ks[cur][krow * 64 + ((32 + lg * 8) ^ swl)]; \
            f32x4 s = (f32x4){0.f, 0.f, 0.f, 0.f};                              \
            s = mfma16(a0, bq0, s);                                             \
            s = mfma16(a1, bq1, s);                                             \
            sacc[mi] = s;                                                       \
        }                                                                       \
        __builtin_amdgcn_s_setprio(0);                                          \
        /* softmax numerator -> P (bf16, own q-rows) */                         \
        _Pragma("unroll")                                                       \
        for (int mi = 0; mi < 4; ++mi) {                                        \
            unsigned mk[4];                                                     \
            if (mode == 1) {                                                    \
                mk[0] = MK1C[mi] & 0xffu;         mk[1] = (MK1C[mi] >> 8) & 0xffu;  \
                mk[2] = (MK1C[mi] >> 16) & 0xffu; mk[3] = (MK1C[mi] >> 24) & 0xffu; \
            } else if (mode == 0) {                                             \
                mk[0] = MK4C[mi].x; mk[1] = MK4C[mi].y;                         \
                mk[2] = MK4C[mi].z; mk[3] = MK4C[mi].w;                         \
            } else {                                                            \
                mk[0] = MK4C[mi].x != 0; mk[1] = MK4C[mi].y != 0;               \
                mk[2] = MK4C[mi].z != 0; mk[3] = MK4C[mi].w != 0;               \
            }                                                                   \
            const float aww[4] = {AWC[mi].x, AWC[mi].y, AWC[mi].z, AWC[mi].w};  \
            float pv[4];                                                        \
            _Pragma("unroll")                                                   \
            for (int r = 0; r < 4; ++r) {                                       \
                float sv = sacc[mi][r] * aww[r];                                \
                pv[r] = mk[r] ? 0.f : __expf(sv);                               \
                psum += pv[r];                                                  \
            }                                                                   \
            uint2 pk;                                                           \
            pk.x = (unsigned)f2bfu(pv[0]) | ((unsigned)f2bfu(pv[1]) << 16);     \
            pk.y = (unsigned)f2bfu(pv[2]) | ((unsigned)f2bfu(pv[3]) << 16);     \
            *(uint2*)&Ps[(wq + lc) * 64 + ((mi * 16 + lg * 4) ^ swl)] = pk;     \
        }                                                                       \
        /* PV */                                                                \
        __builtin_amdgcn_s_setprio(1);                                          \
        _Pragma("unroll")                                                       \
        for (int kk = 0; kk < 2; ++kk) {                                        \
            bf16x8 pa = *(const bf16x8*)&Ps[(wq + lc) * 64 + ((kk * 32 + lg * 8) ^ swl)]; \
            _Pragma("unroll")                                                   \
            for (int nj = 0; nj < 4; ++nj) {                                    \
                bf16x8 vb = *(const bf16x8*)&Vs[cur][(nj * 16 + lc) * 64 + ((kk * 32 + lg * 8) ^ swl)]; \
                oacc[nj] = mfma16(pa, vb, oacc[nj]);                            \
            }                                                                   \
        }                                                                       \
        __builtin_amdgcn_s_setprio(0);                                          \
        if ((T) < 15) {                                                         \
            asm volatile("s_waitcnt vmcnt(0)" ::: "memory");                    \
            __builtin_amdgcn_sched_barrier(0);                                  \
            __builtin_amdgcn_s_barrier();                                       \
        }                                                                       \
    }

    for (int tt = 0; tt < 8; ++tt) {
        const int t0 = tt * 2, t1 = tt * 2 + 1;
        ATTN_BODY(t0, awA, mk4A, mk1A, awB, mk4B, mk1B);
        ATTN_BODY(t1, awB, mk4B, mk1B, awA, mk4A, mk1A);
    }
#undef ATTN_BODY

    psum += __shfl_xor(psum, 16);
    psum += __shfl_xor(psum, 32);
    float inv = 1.0f / psum;
    float invr[4];
    #pragma unroll
    for (int r = 0; r < 4; ++r)
        invr[r] = __shfl(inv, (lane & 48) | (lg * 4 + r));

    #pragma unroll
    for (int nj = 0; nj < 4; ++nj)
        #pragma unroll
        for (int r = 0; r < 4; ++r) {
            int qq = q0 + wq + lg * 4 + r;
            float v = oacc[nj][r] * invr[r];
            ob[(size_t)(b * NN + qq) * DM + h * 64 + nj * 16 + lc] = f2bfu(v);
        }
}

// ---------------------------------------------------------------------------
extern "C" void kernel_launch(void* const* d_in, const int* in_sizes, int n_in,
                              void* d_out, int out_size, void* d_ws, size_t ws_size,
                              hipStream_t stream) {
    const float* xin_f[3] = {(const float*)d_in[0], (const float*)d_in[1], (const float*)d_in[2]};
    const void*  maskp   = d_in[3];
    const float* aw      = (const float*)d_in[4];
    const float* memv    = (const float*)d_in[5];
    const float* Wp_f[3] = {(const float*)d_in[6], (const float*)d_in[8], (const float*)d_in[10]};
    const float* bp[3]   = {(const float*)d_in[7], (const float*)d_in[9], (const float*)d_in[11]};
    const float* Wo_f  = (const float*)d_in[12];  const float* bo  = (const float*)d_in[13];
    const float* Wmm = (const float*)d_in[14];    const float* bmm = (const float*)d_in[15];
    const float* W1f[3] = {(const float*)d_in[16], (const float*)d_in[20], (const float*)d_in[24]};
    const float* b1a[3] = {(const float*)d_in[17], (const float*)d_in[21], (const float*)d_in[25]};
    const float* W2f[3] = {(const float*)d_in[18], (const float*)d_in[22], (const float*)d_in[26]};
    const float* b2a[3] = {(const float*)d_in[19], (const float*)d_in[23], (const float*)d_in[27]};

    char* p = (char*)d_ws;
    auto alloc = [&](size_t bytes) { char* r = p; p += (bytes + 255) & ~(size_t)255; return r; };
    int*    mflags = (int*)alloc(256);
    ushort* xbf[3]; for (int t = 0; t < 3; ++t) xbf[t] = (ushort*)alloc((size_t)TT * DM * 2);
    ushort* Wpb[3]; for (int t = 0; t < 3; ++t) Wpb[t] = (ushort*)alloc((size_t)DM * DM * 2);
    ushort* Wob  = (ushort*)alloc((size_t)DM * DM * 2);
    ushort* W1b[3]; for (int t = 0; t < 3; ++t) W1b[t] = (ushort*)alloc((size_t)HID * DM * 2);
    ushort* W2b[3]; for (int t = 0; t < 3; ++t) W2b[t] = (ushort*)alloc((size_t)DM * HID * 2);
    ushort* hbuf[3]; for (int t = 0; t < 3; ++t) hbuf[t] = (ushort*)alloc((size_t)TT * HID * 2);
    ushort* xg[3];  for (int t = 0; t < 3; ++t) xg[t] = (ushort*)alloc((size_t)TT * DM * 2);
    ushort* qpb  = (ushort*)alloc((size_t)TT * DM * 2);
    ushort* ksb  = (ushort*)alloc((size_t)TT * DM * 2);
    ushort* vtb  = (ushort*)alloc((size_t)TT * DM * 2);
    ushort* obuf = (ushort*)alloc((size_t)TT * DM * 2);

    hipMemsetAsync(mflags, 0, 8, stream);
    detect_mask_kernel<<<256, 256, 0, stream>>>((const uint4*)maskp,
                                                BB * NN * NN / 16, mflags);

    // one merged f32->bf16 conversion dispatch (13 segments)
    {
        CvtAll a;
        const int S_IN = TT * DM / 4, S_W = DM * DM / 4, S_H = HID * DM / 4;
        int idx = 0, cum = 0;
        auto seg = [&](const float* s, ushort* d, int n) {
            a.s[idx] = s; a.d[idx] = d; cum += n; a.bound[idx] = cum; ++idx;
        };
        for (int t = 0; t < 3; ++t) seg(xin_f[t], xbf[t], S_IN);
        for (int t = 0; t < 3; ++t) seg(Wp_f[t], Wpb[t], S_W);
        seg(Wo_f, Wob, S_W);
        for (int t = 0; t < 3; ++t) seg(W1f[t], W1b[t], S_H);
        for (int t = 0; t < 3; ++t) seg(W2f[t], W2b[t], S_H);
        cvt_all<<<2048, 256, 0, stream>>>(a, cum);
    }

    const dim3 blk(256);
    GB g1 = {}, g2 = {}, g3 = {}, g4 = {};
    for (int t = 0; t < 3; ++t) {
        g1.A[t] = xbf[t];  g1.W[t] = W1b[t]; g1.bias[t] = b1a[t]; g1.C[t] = hbuf[t];
        g2.A[t] = hbuf[t]; g2.W[t] = W2b[t]; g2.bias[t] = b2a[t]; g2.C[t] = xg[t]; g2.X[t] = xbf[t];
        g3.A[t] = xg[t];   g3.W[t] = Wpb[t]; g3.bias[t] = bp[t];
    }
    g3.C[0] = qpb; g3.C[1] = ksb; g3.C[2] = vtb;
    g4.A[0] = obuf; g4.W[0] = Wob; g4.bias[0] = bo; g4.C[0] = d_out;

    gemm_bf16<1, 2><<<dim3(TT / 128, HID / 64, 3), blk, 0, stream>>>(g1, TT, HID, DM, nullptr, nullptr, nullptr);
    gemm_bf16<2, 2><<<dim3(TT / 128, DM / 64, 3), blk, 0, stream>>>(g2, TT, DM, HID, nullptr, nullptr, nullptr);
    gemm_bf16<7, 2><<<dim3(TT / 128, DM / 64, 3), blk, 0, stream>>>(g3, TT, DM, DM, memv, Wmm, bmm);

    attn_mfma<<<dim3(1024), blk, 0, stream>>>(qpb, ksb, vtb, aw,
                                              maskp, mflags, obuf);

    gemm_bf16<4, 2><<<dim3(TT / 128, DM / 64, 1), blk, 0, stream>>>(g4, TT, DM, DM, nullptr, nullptr, nullptr);
}